// Round 8
// baseline (22.270 us; speedup 1.0000x reference)
//
#include <hip/hip_runtime.h>
#include <math.h>

#define NN 768
#define FD 16
#define EMB 32
#define HU 64
#define HE 68
#define GAMMA 0.9f

__device__ __forceinline__ float softplus_f(float x) {
    return fmaxf(x, 0.f) + log1pf(__expf(-fabsf(x)));
}

// ---------- Kernel 1: one block per (node, gat-type) ----------------------
// which==0: global GAT -> y_g -> util row/col halves + val head
// which==1: local  GAT -> y_l -> ext  row/col halves
// Single fused neighbor pass: h_j, score, exp, weighted accumulate all
// in-register per 32-lane group (no max-subtraction: |e| is O(1) here,
// softmax is shift-invariant, fp delta ~1e-7 << 3e-2 threshold).
__global__ __launch_bounds__(256) void k_gatheads(
    const float* __restrict__ x, const float* __restrict__ adj,
    const float* __restrict__ Wg, const float* __restrict__ asg, const float* __restrict__ adg,
    const float* __restrict__ Wl, const float* __restrict__ asl, const float* __restrict__ adl,
    const float* __restrict__ uW1, const float* __restrict__ ub1,
    const float* __restrict__ eW1, const float* __restrict__ eb1,
    const float* __restrict__ vW1, const float* __restrict__ vb1,
    const float* __restrict__ vW2, const float* __restrict__ vb2,
    float* __restrict__ urb, float* __restrict__ ucR,
    float* __restrict__ erb, float* __restrict__ ecR,
    float* __restrict__ val, int* __restrict__ nbrg, int* __restrict__ cntg)
{
    int b = blockIdx.x;
    int i = b >> 1, which = b & 1;
    int t = threadIdx.x;
    int lane = t & 63, wid = t >> 6;
    int gid = t >> 5, l32 = t & 31;

    __shared__ float sW[FD * EMB];
    __shared__ float sas[EMB], sad[EMB];
    __shared__ int   s_nbr[NN];
    __shared__ int   s_wcnt[4];
    __shared__ float s_acc[8][EMB + 1];
    __shared__ float s_sum[8];
    __shared__ float s_y[EMB];

    {
        const float* Wsrc = which ? Wl : Wg;
        const float* assrc = which ? asl : asg;
        const float* adsrc = which ? adl : adg;
        for (int k = t; k < FD * EMB; k += 256) sW[k] = Wsrc[k];
        if (t < EMB) { sas[t] = assrc[t]; sad[t] = adsrc[t]; }
    }

    const float* arow = adj + (size_t)i * NN;

    // --- 2-sync deterministic compaction: wave w owns cols [192w,192w+192) ---
    unsigned long long masks[3];
    int wbase = wid * 192;
    int mycnt = 0;
#pragma unroll
    for (int s = 0; s < 3; ++s) {
        int j = wbase + s * 64 + lane;
        bool act = arow[j] > 0.f;
        masks[s] = __ballot(act);
        mycnt += (int)__popcll(masks[s]);
    }
    if (lane == 0) s_wcnt[wid] = mycnt;
    __syncthreads();
    int run = 0;
    for (int w = 0; w < wid; ++w) run += s_wcnt[w];
#pragma unroll
    for (int s = 0; s < 3; ++s) {
        bool act = (masks[s] >> lane) & 1ULL;
        int pos = run + (int)__popcll(masks[s] & ((1ULL << lane) - 1ULL));
        if (act) s_nbr[pos] = wbase + s * 64 + lane;
        run += (int)__popcll(masks[s]);
    }
    __syncthreads();
    int M = s_wcnt[0] + s_wcnt[1] + s_wcnt[2] + s_wcnt[3];

    // own-node source dot (each group computes redundantly; no sync needed)
    float si;
    {
        const float4* x4 = (const float4*)(x + i * FD);
        float4 xa = x4[0], xb = x4[1], xc = x4[2], xd = x4[3];
        float xv[FD] = {xa.x, xa.y, xa.z, xa.w, xb.x, xb.y, xb.z, xb.w,
                        xc.x, xc.y, xc.z, xc.w, xd.x, xd.y, xd.z, xd.w};
        float he = 0.f;
#pragma unroll
        for (int f = 0; f < FD; ++f) he += xv[f] * sW[f * EMB + l32];
        float d = he * sas[l32];
#pragma unroll
        for (int off = 16; off >= 1; off >>= 1) d += __shfl_xor(d, off);
        si = d;
    }

    // single fused neighbor pass (8 groups x 32 lanes, all in-register)
    float acc = 0.f, psum = 0.f;
    for (int c0 = 0; c0 < M; c0 += 8) {
        int idx = c0 + gid;
        if (idx < M) {
            int jn = s_nbr[idx];
            const float4* x4 = (const float4*)(x + jn * FD);
            float4 xa = x4[0], xb = x4[1], xc = x4[2], xd = x4[3];
            float xv[FD] = {xa.x, xa.y, xa.z, xa.w, xb.x, xb.y, xb.z, xb.w,
                            xc.x, xc.y, xc.z, xc.w, xd.x, xd.y, xd.z, xd.w};
            float h = 0.f;
#pragma unroll
            for (int f = 0; f < FD; ++f) h += xv[f] * sW[f * EMB + l32];
            float d = h * sad[l32];
#pragma unroll
            for (int off = 16; off >= 1; off >>= 1) d += __shfl_xor(d, off);
            float e = si + d;
            e = (e > 0.f) ? e : 0.2f * e;            // leaky_relu(0.2)
            float p = __expf(e);                      // no max-shift needed
            acc += p * h;
            psum += p;
        }
    }
    s_acc[gid][l32] = acc;
    if (l32 == 0) s_sum[gid] = psum;
    __syncthreads();
    if (t < EMB) {
        float s = 0.f, sp = 0.f;
#pragma unroll
        for (int g = 0; g < 8; ++g) { s += s_acc[g][t]; sp += s_sum[g]; }
        s_y[t] = s / sp;
    }
    __syncthreads();

    // heads
    if (which == 0) {
        if (t < HU) {
            float r = ub1[t], cc = 0.f;
#pragma unroll
            for (int e = 0; e < EMB; ++e) {
                float y = s_y[e];
                r  += y * uW1[e * HU + t];
                cc += y * uW1[(e + EMB) * HU + t];
            }
            urb[i * HU + t] = r;
            ucR[i * HU + t] = cc;
        } else if (t >= 192) {
            int u = t - 192;
            float v = vb1[u];
#pragma unroll
            for (int e = 0; e < EMB; ++e) v += s_y[e] * vW1[e * 64 + u];
            float rv = fmaxf(v, 0.f) * vW2[u];
#pragma unroll
            for (int off = 32; off >= 1; off >>= 1) rv += __shfl_xor(rv, off);
            if (u == 0) val[i] = -softplus_f(rv + vb2[0]);
        }
        for (int idx = t; idx < M; idx += 256) nbrg[(size_t)i * NN + idx] = s_nbr[idx];
        if (t == 0) cntg[i] = M;
    } else {
        if (t < HE) {
            float r = eb1[t], cc = 0.f;
#pragma unroll
            for (int e = 0; e < EMB; ++e) {
                float y = s_y[e];
                r  += y * eW1[e * HE + t];
                cc += y * eW1[(e + EMB) * HE + t];
            }
            erb[i * HE + t] = r;
            ecR[i * HE + t] = cc;
        }
    }
}

// ---------- Kernel 2: one block per (row, batch); register-resident -------
// No LDS staging: all sub-dependent constants (ur, er, uW2, eW2, w0, w1)
// live in registers (32 threads per sub value -> L1 broadcast loads).
// Exactly ONE __syncthreads (dense-base write must precede edge overwrite).
__global__ __launch_bounds__(256) void k_final(
    const float* __restrict__ pi,
    const float* __restrict__ urb, const float* __restrict__ ucR,
    const float* __restrict__ erb, const float* __restrict__ ecR,
    const float* __restrict__ val,
    const float* __restrict__ uW2, const float* __restrict__ ub2,
    const float* __restrict__ eW1, const float* __restrict__ eb2,
    const float* __restrict__ eW2,
    const int* __restrict__ nbrg, const int* __restrict__ cntg,
    float* __restrict__ out)
{
    int bb = blockIdx.x;
    int i = bb >> 1, bt = bb & 1;          // row, batch
    int t = threadIdx.x;
    int es = t >> 3;                        // edge slot 0..31
    int sub = t & 7;                        // 8 lanes per edge
    int h0 = sub * 8;

    // register-resident per-sub constants
    float4 urA = *(const float4*)(urb + i * HU + h0);
    float4 urB = *(const float4*)(urb + i * HU + h0 + 4);
    float4 uwA = *(const float4*)(uW2 + h0);
    float4 uwB = *(const float4*)(uW2 + h0 + 4);
    float4 erA = *(const float4*)(erb + i * HE + h0);
    float4 erB = *(const float4*)(erb + i * HE + h0 + 4);
    float4 ewA = *(const float4*)(eW2 + h0);
    float4 ewB = *(const float4*)(eW2 + h0 + 4);
    float4 w0A = *(const float4*)(eW1 + (2 * EMB) * HE + h0);
    float4 w0B = *(const float4*)(eW1 + (2 * EMB) * HE + h0 + 4);
    float4 w1A = *(const float4*)(eW1 + (2 * EMB + 1) * HE + h0);
    float4 w1B = *(const float4*)(eW1 + (2 * EMB + 1) * HE + h0 + 4);
    // tail unit 64+sub (sub<4 only)
    int h2 = 64 + sub;
    float er_t = 0.f, ew_t = 0.f, w0_t = 0.f, w1_t = 0.f;
    if (sub < 4) {
        er_t = erb[i * HE + h2];
        ew_t = eW2[h2];
        w0_t = eW1[(2 * EMB) * HE + h2];
        w1_t = eW1[(2 * EMB + 1) * HE + h2];
    }
    float vi = val[i];
    float ub2v = ub2[0], eb2v = eb2[0];

    float* orow = out + ((size_t)bt * NN + i) * NN;

    // dense base: orow[j] = GAMMA*val[j] - vi (float4; threads t<192)
    if (t < NN / 4) {
        float4 vv = ((const float4*)val)[t];
        float4 b;
        b.x = GAMMA * vv.x - vi;
        b.y = GAMMA * vv.y - vi;
        b.z = GAMMA * vv.z - vi;
        b.w = GAMMA * vv.w - vi;
        ((float4*)orow)[t] = b;
    }
    __syncthreads();   // dense write lands before edge overwrite

    int M = cntg[i];
    for (int idx = es; idx < M; idx += 32) {
        int jn = nbrg[(size_t)i * NN + idx];
        // util: units [h0, h0+8)
        const float4* uc4 = (const float4*)(ucR + (size_t)jn * HU);
        float4 u0 = uc4[sub * 2], u1 = uc4[sub * 2 + 1];
        float accu = 0.f;
        accu += fmaxf(urA.x + u0.x, 0.f) * uwA.x;
        accu += fmaxf(urA.y + u0.y, 0.f) * uwA.y;
        accu += fmaxf(urA.z + u0.z, 0.f) * uwA.z;
        accu += fmaxf(urA.w + u0.w, 0.f) * uwA.w;
        accu += fmaxf(urB.x + u1.x, 0.f) * uwB.x;
        accu += fmaxf(urB.y + u1.y, 0.f) * uwB.y;
        accu += fmaxf(urB.z + u1.z, 0.f) * uwB.z;
        accu += fmaxf(urB.w + u1.w, 0.f) * uwB.w;
        // ext for this batch only
        float2 p = *(const float2*)(pi + (((size_t)bt * NN + i) * NN + jn) * 2);
        const float4* ec4 = (const float4*)(ecR + (size_t)jn * HE);
        float4 e0 = ec4[sub * 2], e1 = ec4[sub * 2 + 1];
        float a0 = 0.f;
        a0 += fmaxf(erA.x + e0.x + p.x * w0A.x + p.y * w1A.x, 0.f) * ewA.x;
        a0 += fmaxf(erA.y + e0.y + p.x * w0A.y + p.y * w1A.y, 0.f) * ewA.y;
        a0 += fmaxf(erA.z + e0.z + p.x * w0A.z + p.y * w1A.z, 0.f) * ewA.z;
        a0 += fmaxf(erA.w + e0.w + p.x * w0A.w + p.y * w1A.w, 0.f) * ewA.w;
        a0 += fmaxf(erB.x + e1.x + p.x * w0B.x + p.y * w1B.x, 0.f) * ewB.x;
        a0 += fmaxf(erB.y + e1.y + p.x * w0B.y + p.y * w1B.y, 0.f) * ewB.y;
        a0 += fmaxf(erB.z + e1.z + p.x * w0B.z + p.y * w1B.z, 0.f) * ewB.z;
        a0 += fmaxf(erB.w + e1.w + p.x * w0B.w + p.y * w1B.w, 0.f) * ewB.w;
        if (sub < 4) {
            float ce = er_t + ecR[(size_t)jn * HE + h2];
            a0 += fmaxf(ce + p.x * w0_t + p.y * w1_t, 0.f) * ew_t;
        }
        // reduce across the 8 sub-lanes (xor stays within the 8-lane group)
#pragma unroll
        for (int off = 4; off >= 1; off >>= 1) {
            accu += __shfl_xor(accu, off);
            a0   += __shfl_xor(a0, off);
        }
        if (sub == 0) {
            float util = -softplus_f(accu + ub2v);
            float ext  = -softplus_f(a0 + eb2v);
            orow[jn] = GAMMA * val[jn] - vi + util + ext;
        }
    }
}

extern "C" void kernel_launch(void* const* d_in, const int* in_sizes, int n_in,
                              void* d_out, int out_size, void* d_ws, size_t ws_size,
                              hipStream_t stream) {
    const float* x   = (const float*)d_in[0];
    const float* pi  = (const float*)d_in[2];
    const float* adj = (const float*)d_in[4];
    const float* Wg  = (const float*)d_in[5];
    const float* asg = (const float*)d_in[6];
    const float* adg = (const float*)d_in[7];
    const float* Wl  = (const float*)d_in[8];
    const float* asl = (const float*)d_in[9];
    const float* adl = (const float*)d_in[10];
    const float* uW1 = (const float*)d_in[11];
    const float* ub1 = (const float*)d_in[12];
    const float* uW2 = (const float*)d_in[13];
    const float* ub2 = (const float*)d_in[14];
    const float* eW1 = (const float*)d_in[15];
    const float* eb1 = (const float*)d_in[16];
    const float* eW2 = (const float*)d_in[17];
    const float* eb2 = (const float*)d_in[18];
    const float* vW1 = (const float*)d_in[19];
    const float* vb1 = (const float*)d_in[20];
    const float* vW2 = (const float*)d_in[21];
    const float* vb2 = (const float*)d_in[22];
    float* out = (float*)d_out;

    float* ws = (float*)d_ws;
    float* valp = ws;  ws += NN;
    float* urb  = ws;  ws += NN * HU;
    float* ucR  = ws;  ws += NN * HU;
    float* erb  = ws;  ws += NN * HE;
    float* ecR  = ws;  ws += NN * HE;
    int*   nbrg = (int*)ws;
    int*   cntg = nbrg + (size_t)NN * NN;

    k_gatheads<<<2 * NN, 256, 0, stream>>>(x, adj, Wg, asg, adg, Wl, asl, adl,
                                           uW1, ub1, eW1, eb1, vW1, vb1, vW2, vb2,
                                           urb, ucR, erb, ecR, valp, nbrg, cntg);
    k_final<<<2 * NN, 256, 0, stream>>>(pi, urb, ucR, erb, ecR, valp,
                                        uW2, ub2, eW1, eb2, eW2, nbrg, cntg, out);
}

// Round 9
// 20.745 us; speedup vs baseline: 1.0735x; 1.0735x over previous
//
#include <hip/hip_runtime.h>
#include <math.h>

#define NN 768
#define FD 16
#define EMB 32
#define HU 64
#define HE 68
#define GAMMA 0.9f

__device__ __forceinline__ float softplus_f(float x) {
    return fmaxf(x, 0.f) + log1pf(__expf(-fabsf(x)));
}

// ---------- Kernel 1: one block per (node, gat-type) ----------------------
// which==0: global GAT -> y_g -> util row/col halves + val head
// which==1: local  GAT -> y_l -> ext  row/col halves
// Single fused neighbor pass: h_j, score, exp, weighted accumulate all
// in-register per 32-lane group (no max-subtraction: |e| is O(1) here,
// softmax is shift-invariant, fp delta ~1e-7 << 3e-2 threshold).
__global__ __launch_bounds__(256) void k_gatheads(
    const float* __restrict__ x, const float* __restrict__ adj,
    const float* __restrict__ Wg, const float* __restrict__ asg, const float* __restrict__ adg,
    const float* __restrict__ Wl, const float* __restrict__ asl, const float* __restrict__ adl,
    const float* __restrict__ uW1, const float* __restrict__ ub1,
    const float* __restrict__ eW1, const float* __restrict__ eb1,
    const float* __restrict__ vW1, const float* __restrict__ vb1,
    const float* __restrict__ vW2, const float* __restrict__ vb2,
    float* __restrict__ urb, float* __restrict__ ucR,
    float* __restrict__ erb, float* __restrict__ ecR,
    float* __restrict__ val, int* __restrict__ nbrg, int* __restrict__ cntg)
{
    int b = blockIdx.x;
    int i = b >> 1, which = b & 1;
    int t = threadIdx.x;
    int lane = t & 63, wid = t >> 6;
    int gid = t >> 5, l32 = t & 31;

    __shared__ float sW[FD * EMB];
    __shared__ float sas[EMB], sad[EMB];
    __shared__ int   s_nbr[NN];
    __shared__ int   s_wcnt[4];
    __shared__ float s_acc[8][EMB + 1];
    __shared__ float s_sum[8];
    __shared__ float s_y[EMB];

    {
        const float* Wsrc = which ? Wl : Wg;
        const float* assrc = which ? asl : asg;
        const float* adsrc = which ? adl : adg;
        for (int k = t; k < FD * EMB; k += 256) sW[k] = Wsrc[k];
        if (t < EMB) { sas[t] = assrc[t]; sad[t] = adsrc[t]; }
    }

    const float* arow = adj + (size_t)i * NN;

    // --- 2-sync deterministic compaction: wave w owns cols [192w,192w+192) ---
    unsigned long long masks[3];
    int wbase = wid * 192;
    int mycnt = 0;
#pragma unroll
    for (int s = 0; s < 3; ++s) {
        int j = wbase + s * 64 + lane;
        bool act = arow[j] > 0.f;
        masks[s] = __ballot(act);
        mycnt += (int)__popcll(masks[s]);
    }
    if (lane == 0) s_wcnt[wid] = mycnt;
    __syncthreads();
    int run = 0;
    for (int w = 0; w < wid; ++w) run += s_wcnt[w];
#pragma unroll
    for (int s = 0; s < 3; ++s) {
        bool act = (masks[s] >> lane) & 1ULL;
        int pos = run + (int)__popcll(masks[s] & ((1ULL << lane) - 1ULL));
        if (act) s_nbr[pos] = wbase + s * 64 + lane;
        run += (int)__popcll(masks[s]);
    }
    __syncthreads();
    int M = s_wcnt[0] + s_wcnt[1] + s_wcnt[2] + s_wcnt[3];

    // own-node source dot (each group computes redundantly; no sync needed)
    float si;
    {
        const float4* x4 = (const float4*)(x + i * FD);
        float4 xa = x4[0], xb = x4[1], xc = x4[2], xd = x4[3];
        float xv[FD] = {xa.x, xa.y, xa.z, xa.w, xb.x, xb.y, xb.z, xb.w,
                        xc.x, xc.y, xc.z, xc.w, xd.x, xd.y, xd.z, xd.w};
        float he = 0.f;
#pragma unroll
        for (int f = 0; f < FD; ++f) he += xv[f] * sW[f * EMB + l32];
        float d = he * sas[l32];
#pragma unroll
        for (int off = 16; off >= 1; off >>= 1) d += __shfl_xor(d, off);
        si = d;
    }

    // single fused neighbor pass (8 groups x 32 lanes, all in-register)
    float acc = 0.f, psum = 0.f;
    for (int c0 = 0; c0 < M; c0 += 8) {
        int idx = c0 + gid;
        if (idx < M) {
            int jn = s_nbr[idx];
            const float4* x4 = (const float4*)(x + jn * FD);
            float4 xa = x4[0], xb = x4[1], xc = x4[2], xd = x4[3];
            float xv[FD] = {xa.x, xa.y, xa.z, xa.w, xb.x, xb.y, xb.z, xb.w,
                            xc.x, xc.y, xc.z, xc.w, xd.x, xd.y, xd.z, xd.w};
            float h = 0.f;
#pragma unroll
            for (int f = 0; f < FD; ++f) h += xv[f] * sW[f * EMB + l32];
            float d = h * sad[l32];
#pragma unroll
            for (int off = 16; off >= 1; off >>= 1) d += __shfl_xor(d, off);
            float e = si + d;
            e = (e > 0.f) ? e : 0.2f * e;            // leaky_relu(0.2)
            float p = __expf(e);                      // no max-shift needed
            acc += p * h;
            psum += p;
        }
    }
    s_acc[gid][l32] = acc;
    if (l32 == 0) s_sum[gid] = psum;
    __syncthreads();
    if (t < EMB) {
        float s = 0.f, sp = 0.f;
#pragma unroll
        for (int g = 0; g < 8; ++g) { s += s_acc[g][t]; sp += s_sum[g]; }
        s_y[t] = s / sp;
    }
    __syncthreads();

    // heads
    if (which == 0) {
        if (t < HU) {
            float r = ub1[t], cc = 0.f;
#pragma unroll
            for (int e = 0; e < EMB; ++e) {
                float y = s_y[e];
                r  += y * uW1[e * HU + t];
                cc += y * uW1[(e + EMB) * HU + t];
            }
            urb[i * HU + t] = r;
            ucR[i * HU + t] = cc;
        } else if (t >= 192) {
            int u = t - 192;
            float v = vb1[u];
#pragma unroll
            for (int e = 0; e < EMB; ++e) v += s_y[e] * vW1[e * 64 + u];
            float rv = fmaxf(v, 0.f) * vW2[u];
#pragma unroll
            for (int off = 32; off >= 1; off >>= 1) rv += __shfl_xor(rv, off);
            if (u == 0) val[i] = -softplus_f(rv + vb2[0]);
        }
        for (int idx = t; idx < M; idx += 256) nbrg[(size_t)i * NN + idx] = s_nbr[idx];
        if (t == 0) cntg[i] = M;
    } else {
        if (t < HE) {
            float r = eb1[t], cc = 0.f;
#pragma unroll
            for (int e = 0; e < EMB; ++e) {
                float y = s_y[e];
                r  += y * eW1[e * HE + t];
                cc += y * eW1[(e + EMB) * HE + t];
            }
            erb[i * HE + t] = r;
            ecR[i * HE + t] = cc;
        }
    }
}

// ---------- Kernel 2: dense base write + sparse edges, 8 lanes/edge -------
__global__ __launch_bounds__(256) void k_final(
    const float* __restrict__ pi,
    const float* __restrict__ urb, const float* __restrict__ ucR,
    const float* __restrict__ erb, const float* __restrict__ ecR,
    const float* __restrict__ val,
    const float* __restrict__ uW2, const float* __restrict__ ub2,
    const float* __restrict__ eW1, const float* __restrict__ eb2,
    const float* __restrict__ eW2,
    const int* __restrict__ nbrg, const int* __restrict__ cntg,
    float* __restrict__ out)
{
    int i = blockIdx.x;
    int t = threadIdx.x;
    int lane = t & 63, wid = t >> 6;
    __shared__ float ur_s[HU], uW2s[HU], er_s[HE], eW2s[HE], w0[HE], w1[HE];
    if (t < HU) { ur_s[t] = urb[i * HU + t]; uW2s[t] = uW2[t]; }
    if (t < HE) {
        er_s[t] = erb[i * HE + t];
        eW2s[t] = eW2[t];
        w0[t] = eW1[(2 * EMB) * HE + t];
        w1[t] = eW1[(2 * EMB + 1) * HE + t];
    }
    __syncthreads();

    float vi = val[i];
    // dense base (float4, both batches)
    if (t < NN / 4) {
        float4 vv = ((const float4*)val)[t];
        float4 b;
        b.x = GAMMA * vv.x - vi;
        b.y = GAMMA * vv.y - vi;
        b.z = GAMMA * vv.z - vi;
        b.w = GAMMA * vv.w - vi;
        ((float4*)(out + (size_t)i * NN))[t] = b;
        ((float4*)(out + (size_t)(NN + i) * NN))[t] = b;
    }
    __syncthreads();

    int M = cntg[i];
    float ub2v = ub2[0], eb2v = eb2[0];

    // 8 lanes per edge: es = edge slot (32 per block pass), sub = 0..7
    int es = wid * 8 + (lane >> 3);
    int sub = lane & 7;

    for (int idx = es; idx < M; idx += 32) {
        int jn = nbrg[(size_t)i * NN + idx];
        // util: units [sub*8, sub*8+8)
        const float4* uc4 = (const float4*)(ucR + (size_t)jn * HU);
        float accu = 0.f;
        {
            float4 u0 = uc4[sub * 2], u1 = uc4[sub * 2 + 1];
            int h = sub * 8;
            accu += fmaxf(ur_s[h + 0] + u0.x, 0.f) * uW2s[h + 0];
            accu += fmaxf(ur_s[h + 1] + u0.y, 0.f) * uW2s[h + 1];
            accu += fmaxf(ur_s[h + 2] + u0.z, 0.f) * uW2s[h + 2];
            accu += fmaxf(ur_s[h + 3] + u0.w, 0.f) * uW2s[h + 3];
            accu += fmaxf(ur_s[h + 4] + u1.x, 0.f) * uW2s[h + 4];
            accu += fmaxf(ur_s[h + 5] + u1.y, 0.f) * uW2s[h + 5];
            accu += fmaxf(ur_s[h + 6] + u1.z, 0.f) * uW2s[h + 6];
            accu += fmaxf(ur_s[h + 7] + u1.w, 0.f) * uW2s[h + 7];
        }
        // ext: units [sub*8, sub*8+8) plus unit 64+sub for sub<4
        float2 p0 = *(const float2*)(pi + ((size_t)i * NN + jn) * 2);
        float2 p1 = *(const float2*)(pi + ((size_t)(NN + i) * NN + jn) * 2);
        const float4* ec4 = (const float4*)(ecR + (size_t)jn * HE);
        float a0 = 0.f, a1 = 0.f;
        {
            float4 e0 = ec4[sub * 2], e1 = ec4[sub * 2 + 1];
            int h = sub * 8;
            float c;
            c = er_s[h + 0] + e0.x;
            a0 += fmaxf(c + p0.x * w0[h + 0] + p0.y * w1[h + 0], 0.f) * eW2s[h + 0];
            a1 += fmaxf(c + p1.x * w0[h + 0] + p1.y * w1[h + 0], 0.f) * eW2s[h + 0];
            c = er_s[h + 1] + e0.y;
            a0 += fmaxf(c + p0.x * w0[h + 1] + p0.y * w1[h + 1], 0.f) * eW2s[h + 1];
            a1 += fmaxf(c + p1.x * w0[h + 1] + p1.y * w1[h + 1], 0.f) * eW2s[h + 1];
            c = er_s[h + 2] + e0.z;
            a0 += fmaxf(c + p0.x * w0[h + 2] + p0.y * w1[h + 2], 0.f) * eW2s[h + 2];
            a1 += fmaxf(c + p1.x * w0[h + 2] + p1.y * w1[h + 2], 0.f) * eW2s[h + 2];
            c = er_s[h + 3] + e0.w;
            a0 += fmaxf(c + p0.x * w0[h + 3] + p0.y * w1[h + 3], 0.f) * eW2s[h + 3];
            a1 += fmaxf(c + p1.x * w0[h + 3] + p1.y * w1[h + 3], 0.f) * eW2s[h + 3];
            c = er_s[h + 4] + e1.x;
            a0 += fmaxf(c + p0.x * w0[h + 4] + p0.y * w1[h + 4], 0.f) * eW2s[h + 4];
            a1 += fmaxf(c + p1.x * w0[h + 4] + p1.y * w1[h + 4], 0.f) * eW2s[h + 4];
            c = er_s[h + 5] + e1.y;
            a0 += fmaxf(c + p0.x * w0[h + 5] + p0.y * w1[h + 5], 0.f) * eW2s[h + 5];
            a1 += fmaxf(c + p1.x * w0[h + 5] + p1.y * w1[h + 5], 0.f) * eW2s[h + 5];
            c = er_s[h + 6] + e1.z;
            a0 += fmaxf(c + p0.x * w0[h + 6] + p0.y * w1[h + 6], 0.f) * eW2s[h + 6];
            a1 += fmaxf(c + p1.x * w0[h + 6] + p1.y * w1[h + 6], 0.f) * eW2s[h + 6];
            c = er_s[h + 7] + e1.w;
            a0 += fmaxf(c + p0.x * w0[h + 7] + p0.y * w1[h + 7], 0.f) * eW2s[h + 7];
            a1 += fmaxf(c + p1.x * w0[h + 7] + p1.y * w1[h + 7], 0.f) * eW2s[h + 7];
            if (sub < 4) {
                int h2 = 64 + sub;
                float ce = er_s[h2] + ecR[(size_t)jn * HE + h2];
                a0 += fmaxf(ce + p0.x * w0[h2] + p0.y * w1[h2], 0.f) * eW2s[h2];
                a1 += fmaxf(ce + p1.x * w0[h2] + p1.y * w1[h2], 0.f) * eW2s[h2];
            }
        }
        // reduce across the 8 sub-lanes (xor offsets stay within 8-lane group)
#pragma unroll
        for (int off = 4; off >= 1; off >>= 1) {
            accu += __shfl_xor(accu, off);
            a0   += __shfl_xor(a0, off);
            a1   += __shfl_xor(a1, off);
        }
        if (sub == 0) {
            float util = -softplus_f(accu + ub2v);
            float ext0 = -softplus_f(a0 + eb2v);
            float ext1 = -softplus_f(a1 + eb2v);
            float basej = GAMMA * val[jn] - vi;
            out[(size_t)i * NN + jn]        = basej + util + ext0;
            out[(size_t)(NN + i) * NN + jn] = basej + util + ext1;
        }
    }
}

extern "C" void kernel_launch(void* const* d_in, const int* in_sizes, int n_in,
                              void* d_out, int out_size, void* d_ws, size_t ws_size,
                              hipStream_t stream) {
    const float* x   = (const float*)d_in[0];
    const float* pi  = (const float*)d_in[2];
    const float* adj = (const float*)d_in[4];
    const float* Wg  = (const float*)d_in[5];
    const float* asg = (const float*)d_in[6];
    const float* adg = (const float*)d_in[7];
    const float* Wl  = (const float*)d_in[8];
    const float* asl = (const float*)d_in[9];
    const float* adl = (const float*)d_in[10];
    const float* uW1 = (const float*)d_in[11];
    const float* ub1 = (const float*)d_in[12];
    const float* uW2 = (const float*)d_in[13];
    const float* ub2 = (const float*)d_in[14];
    const float* eW1 = (const float*)d_in[15];
    const float* eb1 = (const float*)d_in[16];
    const float* eW2 = (const float*)d_in[17];
    const float* eb2 = (const float*)d_in[18];
    const float* vW1 = (const float*)d_in[19];
    const float* vb1 = (const float*)d_in[20];
    const float* vW2 = (const float*)d_in[21];
    const float* vb2 = (const float*)d_in[22];
    float* out = (float*)d_out;

    float* ws = (float*)d_ws;
    float* valp = ws;  ws += NN;
    float* urb  = ws;  ws += NN * HU;
    float* ucR  = ws;  ws += NN * HU;
    float* erb  = ws;  ws += NN * HE;
    float* ecR  = ws;  ws += NN * HE;
    int*   nbrg = (int*)ws;
    int*   cntg = nbrg + (size_t)NN * NN;

    k_gatheads<<<2 * NN, 256, 0, stream>>>(x, adj, Wg, asg, adg, Wl, asl, adl,
                                           uW1, ub1, eW1, eb1, vW1, vb1, vW2, vb2,
                                           urb, ucR, erb, ecR, valp, nbrg, cntg);
    k_final<<<NN, 256, 0, stream>>>(pi, urb, ucR, erb, ecR, valp,
                                    uW2, ub2, eW1, eb2, eW2, nbrg, cntg, out);
}